// Round 4
// baseline (2156.919 us; speedup 1.0000x reference)
//
#include <hip/hip_runtime.h>
#include <hip/hip_bf16.h>
#include <math.h>

using f4 = __attribute__((ext_vector_type(4))) float;
using f16x = __attribute__((ext_vector_type(16))) float;
using sh4 = __attribute__((ext_vector_type(4))) short;
using sh8 = __attribute__((ext_vector_type(8))) short;

constexpr int cV = 32000, cC = 1024;
constexpr int cNH = 16, cNKV = 8, cHD = 64;
constexpr int cE = 8, cHID = 2728;
constexpr int cHIDP = 2752;              // cHID padded to 32 (w2 K-loop, zero-filled)
constexpr int cB = 2, cT = 1024, cN = cB * cT;

__device__ inline float dot4(f4 a, f4 b) { return a[0]*b[0] + a[1]*b[1] + a[2]*b[2] + a[3]*b[3]; }

__device__ inline short f2bf(float f) {
  unsigned u = __builtin_bit_cast(unsigned, f);
  u += 0x7fff + ((u >> 16) & 1);          // RNE
  return (short)(u >> 16);
}
__device__ inline float bf2f(short s) {
  return __builtin_bit_cast(float, ((unsigned)(unsigned short)s) << 16);
}

// ---------------- embedding gather ----------------
__global__ void embed_k(const int* __restrict__ idx, const float* __restrict__ wte,
                        float* __restrict__ x)
{
  int n = blockIdx.x, tid = threadIdx.x;
  size_t row = (size_t)idx[n] * cC;
  *(f4*)(x + (size_t)n * cC + tid * 4) = *(const f4*)(wte + row + tid * 4);
}

// ---------------- rmsnorm (fp32 in, bf16 out) ----------------
__global__ __launch_bounds__(256) void rmsnorm_k(const float* __restrict__ in,
                                                 const float* __restrict__ w,
                                                 short* __restrict__ out)
{
  int n = blockIdx.x, tid = threadIdx.x;
  f4 v = *(const f4*)(in + (size_t)n * cC + tid * 4);
  float s = dot4(v, v);
  #pragma unroll
  for (int off = 32; off; off >>= 1) s += __shfl_xor(s, off);
  __shared__ float red[4];
  if ((tid & 63) == 0) red[tid >> 6] = s;
  __syncthreads();
  float tot = red[0] + red[1] + red[2] + red[3];
  float inv = rsqrtf(tot * (1.0f / cC) + 1e-5f);
  f4 wv = *(const f4*)(w + tid * 4);
  f4 o = v * inv * wv;
  sh4 ov = { f2bf(o[0]), f2bf(o[1]), f2bf(o[2]), f2bf(o[3]) };
  *(sh4*)(out + (size_t)n * cC + tid * 4) = ov;
}

// ============ bf16 MFMA GEMM: 128x128 tile, BK=32, 4 waves (2x2) ============
// A: bf16 (ABF=1, lda in shorts) or fp32. B: fp32 (converted in staging).
// EPI: 0 store, 1 +=.  GATH: 0 none; 2 A-row = C-row = list[m].
// grid: x = m-tile (fastest -> co-resident blocks share B panel), y = n-tile, z = expert.
template<int EPI, int GATH, bool ABF>
__global__ __launch_bounds__(256, 2) void mgemm(
    const void* __restrict__ Ap, const float* __restrict__ Bm, float* __restrict__ Cmat,
    int M, int Nc, int K, int Kb, int lda, int ldb, int ldc,
    const int* __restrict__ gidx, const int* __restrict__ gcnt)
{
  const float* Af = (const float*)Ap;
  const short* Ab = (const short*)Ap;
  int Me = M;
  const int* idxp = nullptr;
  if (GATH) {
    int e = blockIdx.z;
    Me = gcnt[e];
    idxp = gidx + (size_t)e * cN;
    Bm += (size_t)e * (size_t)Kb * ldb;
  }
  int m0 = blockIdx.x * 128;
  if (m0 >= Me) return;
  int n0 = blockIdx.y * 128;

  __shared__ short As[128][40];            // [m][k] bf16, stride walks bank groups
  __shared__ short Bs[128][40];            // [n][k] bf16 (transposed at staging)

  int tid = threadIdx.x;
  int lane = tid & 63, wv = tid >> 6;
  int wr = wv >> 1, wc = wv & 1;

  int ar = tid >> 1;
  int ah = (tid & 1) * 16;
  bool arv = (m0 + ar) < Me;
  size_t asrc = 0;
  if (arv) {
    int t = GATH ? idxp[m0 + ar] : (m0 + ar);
    asrc = (size_t)t * lda;
  }
  int bn = (tid >> 3) * 4;
  int bk = (tid & 7) * 4;
  bool bcv = (n0 + bn) < Nc;

  f4 av[4]; sh8 avb[2]; f4 bv[4];
  const sh8 zs = {0,0,0,0,0,0,0,0};
  auto loadT = [&](int k0) {
    if constexpr (ABF) {
      const short* ap = Ab + asrc + k0 + ah;   // K multiple of 32, rows padded
      avb[0] = arv ? *(const sh8*)ap : zs;
      avb[1] = arv ? *(const sh8*)(ap + 8) : zs;
    } else {
      #pragma unroll
      for (int q = 0; q < 4; q++) {
        int col = k0 + ah + q * 4;
        av[q] = (arv && col < K) ? *(const f4*)(Af + asrc + col) : f4{0.f,0.f,0.f,0.f};
      }
    }
    #pragma unroll
    for (int r = 0; r < 4; r++) {
      int kg = k0 + bk + r;
      bv[r] = (bcv && kg < Kb) ? *(const f4*)(Bm + (size_t)kg * ldb + n0 + bn)
                               : f4{0.f,0.f,0.f,0.f};
    }
  };
  auto storeT = [&]() {
    if constexpr (ABF) {
      *(sh8*)&As[ar][ah]     = avb[0];
      *(sh8*)&As[ar][ah + 8] = avb[1];
    } else {
      sh8 lo, hi;
      #pragma unroll
      for (int j = 0; j < 4; j++) {
        lo[j]     = f2bf(av[0][j]);
        lo[4 + j] = f2bf(av[1][j]);
        hi[j]     = f2bf(av[2][j]);
        hi[4 + j] = f2bf(av[3][j]);
      }
      *(sh8*)&As[ar][ah] = lo;
      *(sh8*)&As[ar][ah + 8] = hi;
    }
    #pragma unroll
    for (int j = 0; j < 4; j++) {
      sh4 col = { f2bf(bv[0][j]), f2bf(bv[1][j]), f2bf(bv[2][j]), f2bf(bv[3][j]) };
      *(sh4*)&Bs[bn + j][bk] = col;
    }
  };

  f4 acc[4][4] = {};
  int fr = lane & 15;
  int kb2 = (lane >> 4) * 8;

  loadT(0);
  for (int k0 = 0; k0 < K; k0 += 32) {
    __syncthreads();
    storeT();
    __syncthreads();
    if (k0 + 32 < K) loadT(k0 + 32);
    sh8 af[4], bf[4];
    #pragma unroll
    for (int m = 0; m < 4; m++) af[m] = *(sh8*)&As[wr * 64 + m * 16 + fr][kb2];
    #pragma unroll
    for (int n = 0; n < 4; n++) bf[n] = *(sh8*)&Bs[wc * 64 + n * 16 + fr][kb2];
    #pragma unroll
    for (int m = 0; m < 4; m++)
      #pragma unroll
      for (int n = 0; n < 4; n++)
        acc[m][n] = __builtin_amdgcn_mfma_f32_16x16x32_bf16(af[m], bf[n], acc[m][n], 0, 0, 0);
  }

  int rq = (lane >> 4) * 4;
  #pragma unroll
  for (int m = 0; m < 4; m++) {
    #pragma unroll
    for (int i = 0; i < 4; i++) {
      int mrow = m0 + wr * 64 + m * 16 + rq + i;
      if (mrow >= Me) continue;
      size_t crow = (size_t)(GATH ? idxp[mrow] : mrow) * ldc;
      #pragma unroll
      for (int n = 0; n < 4; n++) {
        int ncol = n0 + wc * 64 + n * 16 + fr;
        if (ncol >= Nc) continue;
        float vv = acc[m][n][i];
        float* p = Cmat + crow + ncol;
        if (EPI == 0) *p = vv;
        else *p += vv;
      }
    }
  }
}

// ======= fused w1+w3 gather GEMM: acts[slot] = silu(h@w1) * (h@w3), bf16 out =======
__global__ __launch_bounds__(256, 2) void mgemm_ff(
    const short* __restrict__ Ab, const float* __restrict__ B1m, const float* __restrict__ B3m,
    short* __restrict__ actsOut,
    const int* __restrict__ gidx, const int* __restrict__ gcnt)
{
  constexpr int K = cC, Nc = cHID, ldaS = cC, ldb = cHID, ldcS = cHIDP;
  int e = blockIdx.z;
  int Me = gcnt[e];
  const int* idxp = gidx + (size_t)e * cN;
  const float* B1 = B1m + (size_t)e * K * ldb;
  const float* B3 = B3m + (size_t)e * K * ldb;
  int m0 = blockIdx.x * 128;
  if (m0 >= Me) return;
  int n0 = blockIdx.y * 128;

  __shared__ short As[128][40];
  __shared__ short Bs1[128][40];
  __shared__ short Bs3[128][40];

  int tid = threadIdx.x;
  int lane = tid & 63, wv = tid >> 6;
  int wr = wv >> 1, wc = wv & 1;

  int ar = tid >> 1, ah = (tid & 1) * 16;
  bool arv = (m0 + ar) < Me;
  size_t asrc = 0;
  if (arv) asrc = (size_t)(idxp[m0 + ar] >> 1) * ldaS;   // slot -> token
  int bn = (tid >> 3) * 4, bk = (tid & 7) * 4;
  bool bcv = (n0 + bn) < Nc;

  sh8 avb[2]; f4 bv1[4], bv3[4];
  const sh8 zs = {0,0,0,0,0,0,0,0};
  auto loadT = [&](int k0) {
    const short* ap = Ab + asrc + k0 + ah;
    avb[0] = arv ? *(const sh8*)ap : zs;
    avb[1] = arv ? *(const sh8*)(ap + 8) : zs;
    #pragma unroll
    for (int r = 0; r < 4; r++) {
      size_t boff = (size_t)(k0 + bk + r) * ldb + n0 + bn;   // k < 1024 always
      bv1[r] = bcv ? *(const f4*)(B1 + boff) : f4{0.f,0.f,0.f,0.f};
      bv3[r] = bcv ? *(const f4*)(B3 + boff) : f4{0.f,0.f,0.f,0.f};
    }
  };
  auto storeT = [&]() {
    *(sh8*)&As[ar][ah]     = avb[0];
    *(sh8*)&As[ar][ah + 8] = avb[1];
    #pragma unroll
    for (int j = 0; j < 4; j++) {
      sh4 c1 = { f2bf(bv1[0][j]), f2bf(bv1[1][j]), f2bf(bv1[2][j]), f2bf(bv1[3][j]) };
      sh4 c3 = { f2bf(bv3[0][j]), f2bf(bv3[1][j]), f2bf(bv3[2][j]), f2bf(bv3[3][j]) };
      *(sh4*)&Bs1[bn + j][bk] = c1;
      *(sh4*)&Bs3[bn + j][bk] = c3;
    }
  };

  f4 acc1[4][4] = {}, acc3[4][4] = {};
  int fr = lane & 15, kb2 = (lane >> 4) * 8;

  loadT(0);
  for (int k0 = 0; k0 < K; k0 += 32) {
    __syncthreads();
    storeT();
    __syncthreads();
    if (k0 + 32 < K) loadT(k0 + 32);
    sh8 af[4], bf1[4], bf3[4];
    #pragma unroll
    for (int m = 0; m < 4; m++) af[m] = *(sh8*)&As[wr * 64 + m * 16 + fr][kb2];
    #pragma unroll
    for (int n = 0; n < 4; n++) {
      bf1[n] = *(sh8*)&Bs1[wc * 64 + n * 16 + fr][kb2];
      bf3[n] = *(sh8*)&Bs3[wc * 64 + n * 16 + fr][kb2];
    }
    #pragma unroll
    for (int m = 0; m < 4; m++)
      #pragma unroll
      for (int n = 0; n < 4; n++) {
        acc1[m][n] = __builtin_amdgcn_mfma_f32_16x16x32_bf16(af[m], bf1[n], acc1[m][n], 0, 0, 0);
        acc3[m][n] = __builtin_amdgcn_mfma_f32_16x16x32_bf16(af[m], bf3[n], acc3[m][n], 0, 0, 0);
      }
  }

  int rq = (lane >> 4) * 4;
  #pragma unroll
  for (int m = 0; m < 4; m++) {
    #pragma unroll
    for (int i = 0; i < 4; i++) {
      int mrow = m0 + wr * 64 + m * 16 + rq + i;
      if (mrow >= Me) continue;
      size_t crow = (size_t)idxp[mrow] * ldcS;
      #pragma unroll
      for (int n = 0; n < 4; n++) {
        int ncol = n0 + wc * 64 + n * 16 + fr;
        if (ncol < cHID) {
          float a1 = acc1[m][n][i], a3 = acc3[m][n][i];
          float vv = a1 / (1.f + __expf(-a1)) * a3;
          actsOut[crow + ncol] = f2bf(vv);
        } else if (ncol < cHIDP) {
          actsOut[crow + ncol] = 0;           // zero K-pad for w2
        }
      }
    }
  }
}

// ---------------- RoPE in place on [N, nh*64] fp32 ----------------
__global__ void rope_k(float* __restrict__ buf, int nh)
{
  int gid = blockIdx.x * 256 + threadIdx.x;
  int i = gid & 31;
  int rest = gid >> 5;
  int h = rest % nh;
  int n = rest / nh;
  int t = n & (cT - 1);
  float fr = __expf(-(float)i * (9.210340371976184f / 32.f));
  float ang = (float)t * fr;
  float sn, cs;
  sincosf(ang, &sn, &cs);
  float* p = buf + (size_t)n * (nh * cHD) + h * cHD + 2 * i;
  float r0 = p[0], r1 = p[1];
  p[0] = r0 * cs - r1 * sn;
  p[1] = r0 * sn + r1 * cs;
}

// ======== MFMA flash attention: block = 64 q-rows, 2 waves x 32 rows ========
__global__ __launch_bounds__(128) void attn_k(const float* __restrict__ qb,
                                              const float* __restrict__ kb,
                                              const float* __restrict__ vb,
                                              short* __restrict__ yb)
{
  int h = blockIdx.y, b = blockIdx.z;
  int qt = (b == 1) ? (15 - blockIdx.x) : blockIdx.x;
  int qb0 = qt * 64;
  int kvh = h >> 1;                        // n_rep = 2
  int tid = threadIdx.x, w = tid >> 6, l = tid & 63;
  int c = l & 31, g = l >> 5;

  __shared__ short Kl[64 * 64];            // [key][d], swizzled 16B slots
  __shared__ short Vt[64 * 64];            // [d][key], swizzled
  __shared__ short Pl[2][32 * 64];         // per-wave P, swizzled

  sh8 aq[4];
  {
    int grow = qb0 + w * 32 + c;
    const float* qp = qb + (size_t)(b * cT + grow) * cC + h * cHD + g * 8;
    #pragma unroll
    for (int k = 0; k < 4; k++) {
      f4 x0 = *(const f4*)(qp + k * 16);
      f4 x1 = *(const f4*)(qp + k * 16 + 4);
      sh8 v;
      #pragma unroll
      for (int j = 0; j < 4; j++) { v[j] = f2bf(x0[j] * 0.125f); v[4 + j] = f2bf(x1[j] * 0.125f); }
      aq[k] = v;
    }
  }

  float m[16], ll[16];
  f16x o0 = {}, o1 = {};
  #pragma unroll
  for (int i = 0; i < 16; i++) { m[i] = -1e30f; ll[i] = 0.f; }

  for (int kt = 0; kt <= qb0; kt += 64) {
    __syncthreads();
    #pragma unroll
    for (int it = 0; it < 4; it++) {
      int s = tid + 128 * it;
      int row = s >> 3, o16 = s & 7;
      const float* kp = kb + (size_t)(b * cT + kt + row) * (cNKV * cHD) + kvh * cHD + o16 * 8;
      f4 x0 = *(const f4*)kp, x1 = *(const f4*)(kp + 4);
      sh8 v;
      #pragma unroll
      for (int j = 0; j < 4; j++) { v[j] = f2bf(x0[j]); v[4 + j] = f2bf(x1[j]); }
      *(sh8*)((char*)Kl + row * 128 + ((o16 ^ (row & 7)) * 16)) = v;
    }
    {
      int p = tid & 31, dh = tid >> 5;
      const float* v0 = vb + (size_t)(b * cT + kt + 2 * p) * (cNKV * cHD) + kvh * cHD + dh * 16;
      const float* v1 = v0 + cNKV * cHD;
      f4 a0[4], a1[4];
      #pragma unroll
      for (int q = 0; q < 4; q++) { a0[q] = *(const f4*)(v0 + q * 4); a1[q] = *(const f4*)(v1 + q * 4); }
      #pragma unroll
      for (int j = 0; j < 16; j++) {
        int d = dh * 16 + j;
        unsigned pk = (unsigned)(unsigned short)f2bf(a0[j >> 2][j & 3])
                    | ((unsigned)(unsigned short)f2bf(a1[j >> 2][j & 3]) << 16);
        *(unsigned*)((char*)Vt + d * 128 + ((p * 4) ^ ((d & 7) << 4))) = pk;
      }
    }
    __syncthreads();

    f16x s0 = {}, s1 = {};
    #pragma unroll
    for (int k = 0; k < 4; k++) {
      int o16 = k * 2 + g;
      sh8 b0 = *(sh8*)((char*)Kl + c * 128 + ((o16 ^ (c & 7)) * 16));
      sh8 b1 = *(sh8*)((char*)Kl + (32 + c) * 128 + ((o16 ^ ((32 + c) & 7)) * 16));
      s0 = __builtin_amdgcn_mfma_f32_32x32x16_bf16(aq[k], b0, s0, 0, 0, 0);
      s1 = __builtin_amdgcn_mfma_f32_32x32x16_bf16(aq[k], b1, s1, 0, 0, 0);
    }

    if (kt + 63 > qb0 + w * 32) {
      #pragma unroll
      for (int i = 0; i < 16; i++) {
        int r = qb0 + w * 32 + (i & 3) + 8 * (i >> 2) + 4 * g;
        if (kt + c > r)      s0[i] = -1e30f;
        if (kt + 32 + c > r) s1[i] = -1e30f;
      }
    }

    #pragma unroll
    for (int i = 0; i < 16; i++) {
      float mt = fmaxf(s0[i], s1[i]);
      #pragma unroll
      for (int off = 1; off < 32; off <<= 1) mt = fmaxf(mt, __shfl_xor(mt, off));
      float mn = fmaxf(m[i], mt);
      float rs = __expf(m[i] - mn);
      m[i] = mn;
      float p0 = __expf(s0[i] - mn);
      float p1 = __expf(s1[i] - mn);
      s0[i] = p0; s1[i] = p1;
      float ps = p0 + p1;
      #pragma unroll
      for (int off = 1; off < 32; off <<= 1) ps += __shfl_xor(ps, off);
      ll[i] = ll[i] * rs + ps;
      o0[i] *= rs; o1[i] *= rs;
    }

    #pragma unroll
    for (int i = 0; i < 16; i++) {
      int r = (i & 3) + 8 * (i >> 2) + 4 * g;
      *(short*)((char*)Pl[w] + r * 128 + ((c * 2) ^ ((r & 7) << 4)))        = f2bf(s0[i]);
      *(short*)((char*)Pl[w] + r * 128 + (((32 + c) * 2) ^ ((r & 7) << 4))) = f2bf(s1[i]);
    }

    #pragma unroll
    for (int k = 0; k < 4; k++) {
      int o16 = k * 2 + g;
      sh8 ap  = *(sh8*)((char*)Pl[w] + c * 128 + ((o16 ^ (c & 7)) * 16));
      sh8 bv0 = *(sh8*)((char*)Vt + c * 128 + ((o16 ^ (c & 7)) * 16));
      sh8 bv1 = *(sh8*)((char*)Vt + (32 + c) * 128 + ((o16 ^ ((32 + c) & 7)) * 16));
      o0 = __builtin_amdgcn_mfma_f32_32x32x16_bf16(ap, bv0, o0, 0, 0, 0);
      o1 = __builtin_amdgcn_mfma_f32_32x32x16_bf16(ap, bv1, o1, 0, 0, 0);
    }
  }

  #pragma unroll
  for (int i = 0; i < 16; i++) {
    int r = qb0 + w * 32 + (i & 3) + 8 * (i >> 2) + 4 * g;
    float inv = 1.0f / ll[i];
    short* yp = yb + (size_t)(b * cT + r) * cC + h * cHD;
    yp[c]      = f2bf(o0[i] * inv);
    yp[32 + c] = f2bf(o1[i] * inv);
  }
}

// ---------------- gate (bf16 h): logits, top-2, softmax, atomic routing ----------------
__global__ __launch_bounds__(256) void gate_k(const short* __restrict__ h2,
                                              const float* __restrict__ gw,
                                              float* __restrict__ selw,
                                              int* __restrict__ cnt, int* __restrict__ elist)
{
  int wv = threadIdx.x >> 6, lane = threadIdx.x & 63;
  int n = blockIdx.x * 4 + wv;
  float acc[8] = {0.f, 0.f, 0.f, 0.f, 0.f, 0.f, 0.f, 0.f};
  for (int c = lane; c < cC; c += 64) {
    float hv = bf2f(h2[(size_t)n * cC + c]);
    f4 g0 = *(const f4*)(gw + c * 8);
    f4 g1 = *(const f4*)(gw + c * 8 + 4);
    acc[0] = fmaf(hv, g0[0], acc[0]); acc[1] = fmaf(hv, g0[1], acc[1]);
    acc[2] = fmaf(hv, g0[2], acc[2]); acc[3] = fmaf(hv, g0[3], acc[3]);
    acc[4] = fmaf(hv, g1[0], acc[4]); acc[5] = fmaf(hv, g1[1], acc[5]);
    acc[6] = fmaf(hv, g1[2], acc[6]); acc[7] = fmaf(hv, g1[3], acc[7]);
  }
  #pragma unroll
  for (int e = 0; e < 8; e++)
    #pragma unroll
    for (int off = 32; off; off >>= 1) acc[e] += __shfl_xor(acc[e], off);
  if (lane == 0) {
    int i0 = 0; float m0 = acc[0];
    #pragma unroll
    for (int e = 1; e < 8; e++) if (acc[e] > m0) { m0 = acc[e]; i0 = e; }
    int i1 = -1; float m1 = -INFINITY;
    #pragma unroll
    for (int e = 0; e < 8; e++) if (e != i0 && acc[e] > m1) { m1 = acc[e]; i1 = e; }
    float e1 = expf(m1 - m0);
    float p0 = 1.f / (1.f + e1);
    float p1 = e1 / (1.f + e1);
    selw[n * 2] = p0;
    selw[n * 2 + 1] = p1;
    int pos0 = atomicAdd(&cnt[i0], 1); elist[(size_t)i0 * cN + pos0] = n * 2;
    int pos1 = atomicAdd(&cnt[i1], 1); elist[(size_t)i1 * cN + pos1] = n * 2 + 1;
  }
}

// ---------------- weighted combine ----------------
__global__ void combine_k(float* __restrict__ x, const float* __restrict__ eo,
                          const float* __restrict__ selw)
{
  int n = blockIdx.x, tid = threadIdx.x;
  float w0 = selw[n * 2], w1 = selw[n * 2 + 1];
  f4 a = *(const f4*)(eo + (size_t)(n * 2) * cC + tid * 4);
  f4 b = *(const f4*)(eo + (size_t)(n * 2 + 1) * cC + tid * 4);
  f4 xv = *(f4*)(x + (size_t)n * cC + tid * 4);
  xv += a * w0 + b * w1;
  *(f4*)(x + (size_t)n * cC + tid * 4) = xv;
}

// ---------------- logits (bf16 h) ----------------
__global__ __launch_bounds__(256) void logits_k(const short* __restrict__ hf,
                                                const float* __restrict__ wte,
                                                float* __restrict__ out)
{
  int wv = threadIdx.x >> 6, lane = threadIdx.x & 63;
  int v = blockIdx.x * 4 + wv;
  const float* wrow = wte + (size_t)v * cC;
  const short* r0 = hf + (size_t)(cT - 1) * cC;
  const short* r1 = hf + (size_t)(2 * cT - 1) * cC;
  float a0 = 0.f, a1 = 0.f;
  for (int c = lane * 4; c < cC; c += 256) {
    f4 w4 = *(const f4*)(wrow + c);
    sh4 s0 = *(const sh4*)(r0 + c);
    sh4 s1 = *(const sh4*)(r1 + c);
    #pragma unroll
    for (int j = 0; j < 4; j++) {
      a0 = fmaf(w4[j], bf2f(s0[j]), a0);
      a1 = fmaf(w4[j], bf2f(s1[j]), a1);
    }
  }
  #pragma unroll
  for (int off = 32; off; off >>= 1) { a0 += __shfl_xor(a0, off); a1 += __shfl_xor(a1, off); }
  if (lane == 0) { out[v] = a0; out[cV + v] = a1; }
}

// =======================================================================
extern "C" void kernel_launch(void* const* d_in, const int* in_sizes, int n_in,
                              void* d_out, int out_size, void* d_ws, size_t ws_size,
                              hipStream_t stream)
{
  (void)in_sizes; (void)n_in; (void)out_size;
  const int*   idx  = (const int*)  d_in[0];
  const float* wte  = (const float*)d_in[1];
  const float* ln1w = (const float*)d_in[2];
  const float* p_wq = (const float*)d_in[3];
  const float* p_wk = (const float*)d_in[4];
  const float* p_wv = (const float*)d_in[5];
  const float* p_wo = (const float*)d_in[6];
  const float* ln2w = (const float*)d_in[7];
  const float* gw   = (const float*)d_in[8];
  const float* w1   = (const float*)d_in[9];
  const float* w2   = (const float*)d_in[10];
  const float* w3   = (const float*)d_in[11];
  const float* lnfw = (const float*)d_in[12];
  float* out = (float*)d_out;

  float* ws = (float*)d_ws;
  size_t o = 0;
  float* x    = ws + o; o += (size_t)cN * cC;                 // fp32 residual
  short* h    = (short*)(ws + o); o += (size_t)cN * cC / 2;   // bf16
  float* q    = ws + o; o += (size_t)cN * cC;
  float* kbuf = ws + o; o += (size_t)cN * cNKV * cHD;
  float* vbuf = ws + o; o += (size_t)cN * cNKV * cHD;
  short* y    = (short*)(ws + o); o += (size_t)cN * cC / 2;   // bf16
  short* acts = (short*)(ws + o); o += (size_t)cN * 2 * cHIDP / 2;  // bf16, padded
  float* eo   = ws + o; o += (size_t)cN * 2 * cC;
  float* selw = ws + o; o += (size_t)cN * 2;
  int* cnt    = (int*)(ws + o); o += 8;
  int* elist  = (int*)(ws + o); o += (size_t)cE * cN;
  if (ws_size < o * sizeof(float)) return;   // ~65 MB needed

  embed_k<<<cN, 256, 0, stream>>>(idx, wte, x);

  for (int l = 0; l < 2; l++) {
    // ---- attention ----
    rmsnorm_k<<<cN, 256, 0, stream>>>(x, ln1w + (size_t)l * cC, h);
    mgemm<0,0,true><<<dim3(16, 8), 256, 0, stream>>>(h, p_wq + (size_t)l * cC * 1024, q,
        cN, 1024, cC, cC, cC, 1024, 1024, nullptr, nullptr);
    mgemm<0,0,true><<<dim3(16, 4), 256, 0, stream>>>(h, p_wk + (size_t)l * cC * 512, kbuf,
        cN, 512, cC, cC, cC, 512, 512, nullptr, nullptr);
    mgemm<0,0,true><<<dim3(16, 4), 256, 0, stream>>>(h, p_wv + (size_t)l * cC * 512, vbuf,
        cN, 512, cC, cC, cC, 512, 512, nullptr, nullptr);
    rope_k<<<(cN * cNH * 32) / 256, 256, 0, stream>>>(q, cNH);
    rope_k<<<(cN * cNKV * 32) / 256, 256, 0, stream>>>(kbuf, cNKV);
    attn_k<<<dim3(16, cNH, cB), 128, 0, stream>>>(q, kbuf, vbuf, y);
    mgemm<1,0,true><<<dim3(16, 8), 256, 0, stream>>>(y, p_wo + (size_t)l * 1024 * cC, x,
        cN, cC, 1024, 1024, 1024, cC, cC, nullptr, nullptr);   // x += y @ wo

    // ---- MoE ----
    rmsnorm_k<<<cN, 256, 0, stream>>>(x, ln2w + (size_t)l * cC, h);
    hipMemsetAsync(cnt, 0, cE * sizeof(int), stream);
    gate_k<<<cN / 4, 256, 0, stream>>>(h, gw + (size_t)l * cC * cE, selw, cnt, elist);
    // acts[slot] = silu(h @ w1[e]) * (h @ w3[e])   (fused, bf16 out, K-padded)
    mgemm_ff<<<dim3(16, 22, 8), 256, 0, stream>>>(h,
        w1 + (size_t)l * cE * cC * cHID, w3 + (size_t)l * cE * cC * cHID, acts, elist, cnt);
    // eo[slot] = acts[slot] @ w2[e]
    mgemm<0,2,true><<<dim3(16, 8, 8), 256, 0, stream>>>(acts, w2 + (size_t)l * cE * cHID * cC, eo,
        0, cC, cHIDP, cHID, cHIDP, 1024, cC, elist, cnt);
    combine_k<<<cN, 256, 0, stream>>>(x, eo, selw);
  }

  rmsnorm_k<<<cN, 256, 0, stream>>>(x, lnfw, h);
  logits_k<<<cV / 4, 256, 0, stream>>>(h, wte, out);
}

// Round 5
// 1563.533 us; speedup vs baseline: 1.3795x; 1.3795x over previous
//
#include <hip/hip_runtime.h>
#include <hip/hip_bf16.h>
#include <math.h>

using f4 = __attribute__((ext_vector_type(4))) float;
using f16x = __attribute__((ext_vector_type(16))) float;
using sh4 = __attribute__((ext_vector_type(4))) short;
using sh8 = __attribute__((ext_vector_type(8))) short;

constexpr int cV = 32000, cC = 1024;
constexpr int cNH = 16, cNKV = 8, cHD = 64;
constexpr int cE = 8, cHID = 2728;
constexpr int cHIDP = 2752;              // cHID padded to 32 (w2 K-loop, zero-filled)
constexpr int cB = 2, cT = 1024, cN = cB * cT;

__device__ inline float dot4(f4 a, f4 b) { return a[0]*b[0] + a[1]*b[1] + a[2]*b[2] + a[3]*b[3]; }

__device__ inline short f2bf(float f) {
  unsigned u = __builtin_bit_cast(unsigned, f);
  u += 0x7fff + ((u >> 16) & 1);          // RNE
  return (short)(u >> 16);
}
__device__ inline float bf2f(short s) {
  return __builtin_bit_cast(float, ((unsigned)(unsigned short)s) << 16);
}

// ---------------- embedding gather ----------------
__global__ void embed_k(const int* __restrict__ idx, const float* __restrict__ wte,
                        float* __restrict__ x)
{
  int n = blockIdx.x, tid = threadIdx.x;
  size_t row = (size_t)idx[n] * cC;
  *(f4*)(x + (size_t)n * cC + tid * 4) = *(const f4*)(wte + row + tid * 4);
}

// ---------------- rmsnorm (fp32 in, bf16 out) ----------------
__global__ __launch_bounds__(256) void rmsnorm_k(const float* __restrict__ in,
                                                 const float* __restrict__ w,
                                                 short* __restrict__ out)
{
  int n = blockIdx.x, tid = threadIdx.x;
  f4 v = *(const f4*)(in + (size_t)n * cC + tid * 4);
  float s = dot4(v, v);
  #pragma unroll
  for (int off = 32; off; off >>= 1) s += __shfl_xor(s, off);
  __shared__ float red[4];
  if ((tid & 63) == 0) red[tid >> 6] = s;
  __syncthreads();
  float tot = red[0] + red[1] + red[2] + red[3];
  float inv = rsqrtf(tot * (1.0f / cC) + 1e-5f);
  f4 wv = *(const f4*)(w + tid * 4);
  f4 o = v * inv * wv;
  sh4 ov = { f2bf(o[0]), f2bf(o[1]), f2bf(o[2]), f2bf(o[3]) };
  *(sh4*)(out + (size_t)n * cC + tid * 4) = ov;
}

// ------------- transpose + fp32->bf16 convert: src[K][N] -> dst[N][Kp] -------------
// Kp multiple of 32; k in [K,Kp) zero-filled. grid: (Kp/32, ceil(N/32), nmat)
__global__ __launch_bounds__(256) void convT_k(const float* __restrict__ src,
                                               short* __restrict__ dst,
                                               int K, int N, int Kp)
{
  int z = blockIdx.z;
  src += (size_t)z * K * N;
  dst += (size_t)z * N * Kp;
  int k0 = blockIdx.x * 32, n0 = blockIdx.y * 32;
  __shared__ float T[32][33];
  int r = threadIdx.x >> 3, cq = (threadIdx.x & 7) * 4;
  f4 v = {0.f, 0.f, 0.f, 0.f};
  if (k0 + r < K && n0 + cq < N)          // N%4==0 -> full f4 or none
    v = *(const f4*)(src + (size_t)(k0 + r) * N + n0 + cq);
  T[r][cq + 0] = v[0]; T[r][cq + 1] = v[1]; T[r][cq + 2] = v[2]; T[r][cq + 3] = v[3];
  __syncthreads();
  int n = n0 + r;
  if (n < N) {
    sh4 ov = { f2bf(T[cq + 0][r]), f2bf(T[cq + 1][r]), f2bf(T[cq + 2][r]), f2bf(T[cq + 3][r]) };
    *(sh4*)(dst + (size_t)n * Kp + k0 + cq) = ov;
  }
}

// ============ bf16 MFMA GEMM: 128x128 tile, BK=32, 4 waves (2x2) ============
// A: bf16 [row][Kloop] (rows padded, lda in shorts).
// B: BT=1 -> bf16 [n][Kp] (ldb = Kp, shorts); BT=0 -> fp32 [k][n] (ldb = N, floats).
// EPI: 0 store, 1 +=.  GATH: 0 none; 2 A-row = C-row = list[m].
// grid: x = m-tile (fastest -> co-resident blocks share B panel), y = n-tile, z = expert.
template<int EPI, int GATH, bool BT>
__global__ __launch_bounds__(256, 2) void mgemm(
    const short* __restrict__ Ab, const void* __restrict__ Bp, float* __restrict__ Cmat,
    int M, int Nc, int Kloop, int Kreal, int lda, int ldb, int ldc,
    const int* __restrict__ gidx, const int* __restrict__ gcnt)
{
  int Me = M;
  const int* idxp = nullptr;
  size_t boff0 = 0;
  if (GATH) {
    int e = blockIdx.z;
    Me = gcnt[e];
    idxp = gidx + (size_t)e * cN;
    boff0 = (size_t)e * (BT ? (size_t)Nc * ldb : (size_t)Kreal * ldb);
  }
  int m0 = blockIdx.x * 128;
  if (m0 >= Me) return;
  int n0 = blockIdx.y * 128;

  __shared__ short As[128][40];            // [m][k] bf16 (80B stride walks bank groups)
  __shared__ short Bs[128][40];            // [n][k] bf16

  int tid = threadIdx.x;
  int lane = tid & 63, wv = tid >> 6;
  int wr = wv >> 1, wc = wv & 1;

  int ar = tid >> 1;
  int ah = (tid & 1) * 16;
  bool arv = (m0 + ar) < Me;
  size_t asrc = 0;
  if (arv) {
    int t = GATH ? idxp[m0 + ar] : (m0 + ar);
    asrc = (size_t)t * lda;
  }

  const sh8 zs = {0,0,0,0,0,0,0,0};
  sh8 avb[2], bvb[2];
  f4 bv[4];
  // !BT staging map
  int bn = (tid >> 3) * 4;
  int bk = (tid & 7) * 4;
  bool bcv = (n0 + bn) < Nc;
  // BT staging map (same pattern as A)
  bool brv = (n0 + ar) < Nc;
  const short* BtRow = (const short*)Bp + boff0 + (size_t)(n0 + ar) * ldb;
  const float* Bf = (const float*)Bp + boff0;

  auto loadT = [&](int k0) {
    avb[0] = arv ? *(const sh8*)(Ab + asrc + k0 + ah) : zs;
    avb[1] = arv ? *(const sh8*)(Ab + asrc + k0 + ah + 8) : zs;
    if constexpr (BT) {
      bvb[0] = brv ? *(const sh8*)(BtRow + k0 + ah) : zs;
      bvb[1] = brv ? *(const sh8*)(BtRow + k0 + ah + 8) : zs;
    } else {
      #pragma unroll
      for (int r2 = 0; r2 < 4; r2++) {
        int kg = k0 + bk + r2;
        bv[r2] = (bcv && kg < Kreal) ? *(const f4*)(Bf + (size_t)kg * ldb + n0 + bn)
                                     : f4{0.f,0.f,0.f,0.f};
      }
    }
  };
  auto storeT = [&]() {
    *(sh8*)&As[ar][ah]     = avb[0];
    *(sh8*)&As[ar][ah + 8] = avb[1];
    if constexpr (BT) {
      *(sh8*)&Bs[ar][ah]     = bvb[0];
      *(sh8*)&Bs[ar][ah + 8] = bvb[1];
    } else {
      #pragma unroll
      for (int j = 0; j < 4; j++) {
        sh4 col = { f2bf(bv[0][j]), f2bf(bv[1][j]), f2bf(bv[2][j]), f2bf(bv[3][j]) };
        *(sh4*)&Bs[bn + j][bk] = col;
      }
    }
  };

  f4 acc[4][4] = {};
  int fr = lane & 15;
  int kb2 = (lane >> 4) * 8;

  loadT(0);
  for (int k0 = 0; k0 < Kloop; k0 += 32) {
    __syncthreads();
    storeT();
    __syncthreads();
    if (k0 + 32 < Kloop) loadT(k0 + 32);
    sh8 af[4], bf[4];
    #pragma unroll
    for (int m = 0; m < 4; m++) af[m] = *(sh8*)&As[wr * 64 + m * 16 + fr][kb2];
    #pragma unroll
    for (int n = 0; n < 4; n++) bf[n] = *(sh8*)&Bs[wc * 64 + n * 16 + fr][kb2];
    #pragma unroll
    for (int m = 0; m < 4; m++)
      #pragma unroll
      for (int n = 0; n < 4; n++)
        acc[m][n] = __builtin_amdgcn_mfma_f32_16x16x32_bf16(af[m], bf[n], acc[m][n], 0, 0, 0);
  }

  int rq = (lane >> 4) * 4;
  #pragma unroll
  for (int m = 0; m < 4; m++) {
    #pragma unroll
    for (int i = 0; i < 4; i++) {
      int mrow = m0 + wr * 64 + m * 16 + rq + i;
      if (mrow >= Me) continue;
      size_t crow = (size_t)(GATH ? idxp[mrow] : mrow) * ldc;
      #pragma unroll
      for (int n = 0; n < 4; n++) {
        int ncol = n0 + wc * 64 + n * 16 + fr;
        if (ncol >= Nc) continue;
        float vv = acc[m][n][i];
        float* p = Cmat + crow + ncol;
        if (EPI == 0) *p = vv;
        else *p += vv;
      }
    }
  }
}

// ======= fused w1+w3 gather GEMM: acts[slot] = silu(h@w1) * (h@w3), bf16 out =======
template<bool BT>
__global__ __launch_bounds__(256, 2) void mgemm_ff(
    const short* __restrict__ Ab, const void* __restrict__ B1p, const void* __restrict__ B3p,
    short* __restrict__ actsOut,
    const int* __restrict__ gidx, const int* __restrict__ gcnt)
{
  constexpr int K = cC, Nc = cHID;
  constexpr int ldbT = cC;                 // BT row stride (shorts)
  constexpr int ldbF = cHID;               // !BT row stride (floats)
  int e = blockIdx.z;
  int Me = gcnt[e];
  const int* idxp = gidx + (size_t)e * cN;
  int m0 = blockIdx.x * 128;
  if (m0 >= Me) return;
  int n0 = blockIdx.y * 128;

  __shared__ short As[128][40];
  __shared__ short Bs1[128][40];
  __shared__ short Bs3[128][40];

  int tid = threadIdx.x;
  int lane = tid & 63, wv = tid >> 6;
  int wr = wv >> 1, wc = wv & 1;

  int ar = tid >> 1, ah = (tid & 1) * 16;
  bool arv = (m0 + ar) < Me;
  size_t asrc = 0;
  if (arv) asrc = (size_t)(idxp[m0 + ar] >> 1) * cC;     // slot -> token

  const sh8 zs = {0,0,0,0,0,0,0,0};
  sh8 avb[2], b1b[2], b3b[2];
  f4 bv1[4], bv3[4];
  // !BT map
  int bn = (tid >> 3) * 4, bk = (tid & 7) * 4;
  bool bcv = (n0 + bn) < Nc;
  const float* B1f = (const float*)B1p + (size_t)e * K * ldbF;
  const float* B3f = (const float*)B3p + (size_t)e * K * ldbF;
  // BT map
  bool brv = (n0 + ar) < Nc;
  const short* B1t = (const short*)B1p + (size_t)e * Nc * ldbT + (size_t)(n0 + ar) * ldbT;
  const short* B3t = (const short*)B3p + (size_t)e * Nc * ldbT + (size_t)(n0 + ar) * ldbT;

  auto loadT = [&](int k0) {
    avb[0] = arv ? *(const sh8*)(Ab + asrc + k0 + ah) : zs;
    avb[1] = arv ? *(const sh8*)(Ab + asrc + k0 + ah + 8) : zs;
    if constexpr (BT) {
      b1b[0] = brv ? *(const sh8*)(B1t + k0 + ah) : zs;
      b1b[1] = brv ? *(const sh8*)(B1t + k0 + ah + 8) : zs;
      b3b[0] = brv ? *(const sh8*)(B3t + k0 + ah) : zs;
      b3b[1] = brv ? *(const sh8*)(B3t + k0 + ah + 8) : zs;
    } else {
      #pragma unroll
      for (int r2 = 0; r2 < 4; r2++) {
        size_t boff = (size_t)(k0 + bk + r2) * ldbF + n0 + bn;
        bv1[r2] = bcv ? *(const f4*)(B1f + boff) : f4{0.f,0.f,0.f,0.f};
        bv3[r2] = bcv ? *(const f4*)(B3f + boff) : f4{0.f,0.f,0.f,0.f};
      }
    }
  };
  auto storeT = [&]() {
    *(sh8*)&As[ar][ah]     = avb[0];
    *(sh8*)&As[ar][ah + 8] = avb[1];
    if constexpr (BT) {
      *(sh8*)&Bs1[ar][ah]     = b1b[0];
      *(sh8*)&Bs1[ar][ah + 8] = b1b[1];
      *(sh8*)&Bs3[ar][ah]     = b3b[0];
      *(sh8*)&Bs3[ar][ah + 8] = b3b[1];
    } else {
      #pragma unroll
      for (int j = 0; j < 4; j++) {
        sh4 c1 = { f2bf(bv1[0][j]), f2bf(bv1[1][j]), f2bf(bv1[2][j]), f2bf(bv1[3][j]) };
        sh4 c3 = { f2bf(bv3[0][j]), f2bf(bv3[1][j]), f2bf(bv3[2][j]), f2bf(bv3[3][j]) };
        *(sh4*)&Bs1[bn + j][bk] = c1;
        *(sh4*)&Bs3[bn + j][bk] = c3;
      }
    }
  };

  f4 acc1[4][4] = {}, acc3[4][4] = {};
  int fr = lane & 15, kb2 = (lane >> 4) * 8;

  loadT(0);
  for (int k0 = 0; k0 < K; k0 += 32) {
    __syncthreads();
    storeT();
    __syncthreads();
    if (k0 + 32 < K) loadT(k0 + 32);
    sh8 af[4], bf1[4], bf3[4];
    #pragma unroll
    for (int m = 0; m < 4; m++) af[m] = *(sh8*)&As[wr * 64 + m * 16 + fr][kb2];
    #pragma unroll
    for (int n = 0; n < 4; n++) {
      bf1[n] = *(sh8*)&Bs1[wc * 64 + n * 16 + fr][kb2];
      bf3[n] = *(sh8*)&Bs3[wc * 64 + n * 16 + fr][kb2];
    }
    #pragma unroll
    for (int m = 0; m < 4; m++)
      #pragma unroll
      for (int n = 0; n < 4; n++) {
        acc1[m][n] = __builtin_amdgcn_mfma_f32_16x16x32_bf16(af[m], bf1[n], acc1[m][n], 0, 0, 0);
        acc3[m][n] = __builtin_amdgcn_mfma_f32_16x16x32_bf16(af[m], bf3[n], acc3[m][n], 0, 0, 0);
      }
  }

  int rq = (lane >> 4) * 4;
  #pragma unroll
  for (int m = 0; m < 4; m++) {
    #pragma unroll
    for (int i = 0; i < 4; i++) {
      int mrow = m0 + wr * 64 + m * 16 + rq + i;
      if (mrow >= Me) continue;
      size_t crow = (size_t)idxp[mrow] * cHIDP;
      #pragma unroll
      for (int n = 0; n < 4; n++) {
        int ncol = n0 + wc * 64 + n * 16 + fr;
        if (ncol < cHID) {
          float a1 = acc1[m][n][i], a3 = acc3[m][n][i];
          float vv = a1 / (1.f + __expf(-a1)) * a3;
          actsOut[crow + ncol] = f2bf(vv);
        } else if (ncol < cHIDP) {
          actsOut[crow + ncol] = 0;           // zero K-pad for w2
        }
      }
    }
  }
}

// ---------------- RoPE in place on [N, nh*64] fp32 ----------------
__global__ void rope_k(float* __restrict__ buf, int nh)
{
  int gid = blockIdx.x * 256 + threadIdx.x;
  int i = gid & 31;
  int rest = gid >> 5;
  int h = rest % nh;
  int n = rest / nh;
  int t = n & (cT - 1);
  float fr = __expf(-(float)i * (9.210340371976184f / 32.f));
  float ang = (float)t * fr;
  float sn, cs;
  sincosf(ang, &sn, &cs);
  float* p = buf + (size_t)n * (nh * cHD) + h * cHD + 2 * i;
  float r0 = p[0], r1 = p[1];
  p[0] = r0 * cs - r1 * sn;
  p[1] = r0 * sn + r1 * cs;
}

// ======== MFMA flash attention: block = 64 q-rows, 2 waves x 32 rows ========
__global__ __launch_bounds__(128) void attn_k(const float* __restrict__ qb,
                                              const float* __restrict__ kb,
                                              const float* __restrict__ vb,
                                              short* __restrict__ yb)
{
  int h = blockIdx.y, b = blockIdx.z;
  int qt = (b == 1) ? (15 - blockIdx.x) : blockIdx.x;
  int qb0 = qt * 64;
  int kvh = h >> 1;                        // n_rep = 2
  int tid = threadIdx.x, w = tid >> 6, l = tid & 63;
  int c = l & 31, g = l >> 5;

  __shared__ short Kl[64 * 64];            // [key][d], swizzled 16B slots
  __shared__ short Vt[64 * 64];            // [d][key], swizzled
  __shared__ short Pl[2][32 * 64];         // per-wave P, swizzled

  sh8 aq[4];
  {
    int grow = qb0 + w * 32 + c;
    const float* qp = qb + (size_t)(b * cT + grow) * cC + h * cHD + g * 8;
    #pragma unroll
    for (int k = 0; k < 4; k++) {
      f4 x0 = *(const f4*)(qp + k * 16);
      f4 x1 = *(const f4*)(qp + k * 16 + 4);
      sh8 v;
      #pragma unroll
      for (int j = 0; j < 4; j++) { v[j] = f2bf(x0[j] * 0.125f); v[4 + j] = f2bf(x1[j] * 0.125f); }
      aq[k] = v;
    }
  }

  float m[16], ll[16];
  f16x o0 = {}, o1 = {};
  #pragma unroll
  for (int i = 0; i < 16; i++) { m[i] = -1e30f; ll[i] = 0.f; }

  for (int kt = 0; kt <= qb0; kt += 64) {
    __syncthreads();
    #pragma unroll
    for (int it = 0; it < 4; it++) {
      int s = tid + 128 * it;
      int row = s >> 3, o16 = s & 7;
      const float* kp = kb + (size_t)(b * cT + kt + row) * (cNKV * cHD) + kvh * cHD + o16 * 8;
      f4 x0 = *(const f4*)kp, x1 = *(const f4*)(kp + 4);
      sh8 v;
      #pragma unroll
      for (int j = 0; j < 4; j++) { v[j] = f2bf(x0[j]); v[4 + j] = f2bf(x1[j]); }
      *(sh8*)((char*)Kl + row * 128 + ((o16 ^ (row & 7)) * 16)) = v;
    }
    {
      int p = tid & 31, dh = tid >> 5;
      const float* v0 = vb + (size_t)(b * cT + kt + 2 * p) * (cNKV * cHD) + kvh * cHD + dh * 16;
      const float* v1 = v0 + cNKV * cHD;
      f4 a0[4], a1[4];
      #pragma unroll
      for (int q = 0; q < 4; q++) { a0[q] = *(const f4*)(v0 + q * 4); a1[q] = *(const f4*)(v1 + q * 4); }
      #pragma unroll
      for (int j = 0; j < 16; j++) {
        int d = dh * 16 + j;
        unsigned pk = (unsigned)(unsigned short)f2bf(a0[j >> 2][j & 3])
                    | ((unsigned)(unsigned short)f2bf(a1[j >> 2][j & 3]) << 16);
        *(unsigned*)((char*)Vt + d * 128 + ((p * 4) ^ ((d & 7) << 4))) = pk;
      }
    }
    __syncthreads();

    f16x s0 = {}, s1 = {};
    #pragma unroll
    for (int k = 0; k < 4; k++) {
      int o16 = k * 2 + g;
      sh8 b0 = *(sh8*)((char*)Kl + c * 128 + ((o16 ^ (c & 7)) * 16));
      sh8 b1 = *(sh8*)((char*)Kl + (32 + c) * 128 + ((o16 ^ ((32 + c) & 7)) * 16));
      s0 = __builtin_amdgcn_mfma_f32_32x32x16_bf16(aq[k], b0, s0, 0, 0, 0);
      s1 = __builtin_amdgcn_mfma_f32_32x32x16_bf16(aq[k], b1, s1, 0, 0, 0);
    }

    if (kt + 63 > qb0 + w * 32) {
      #pragma unroll
      for (int i = 0; i < 16; i++) {
        int r = qb0 + w * 32 + (i & 3) + 8 * (i >> 2) + 4 * g;
        if (kt + c > r)      s0[i] = -1e30f;
        if (kt + 32 + c > r) s1[i] = -1e30f;
      }
    }

    #pragma unroll
    for (int i = 0; i < 16; i++) {
      float mt = fmaxf(s0[i], s1[i]);
      #pragma unroll
      for (int off = 1; off < 32; off <<= 1) mt = fmaxf(mt, __shfl_xor(mt, off));
      float mn = fmaxf(m[i], mt);
      float rs = __expf(m[i] - mn);
      m[i] = mn;
      float p0 = __expf(s0[i] - mn);
      float p1 = __expf(s1[i] - mn);
      s0[i] = p0; s1[i] = p1;
      float ps = p0 + p1;
      #pragma unroll
      for (int off = 1; off < 32; off <<= 1) ps += __shfl_xor(ps, off);
      ll[i] = ll[i] * rs + ps;
      o0[i] *= rs; o1[i] *= rs;
    }

    #pragma unroll
    for (int i = 0; i < 16; i++) {
      int r = (i & 3) + 8 * (i >> 2) + 4 * g;
      *(short*)((char*)Pl[w] + r * 128 + ((c * 2) ^ ((r & 7) << 4)))        = f2bf(s0[i]);
      *(short*)((char*)Pl[w] + r * 128 + (((32 + c) * 2) ^ ((r & 7) << 4))) = f2bf(s1[i]);
    }

    #pragma unroll
    for (int k = 0; k < 4; k++) {
      int o16 = k * 2 + g;
      sh8 ap  = *(sh8*)((char*)Pl[w] + c * 128 + ((o16 ^ (c & 7)) * 16));
      sh8 bv0 = *(sh8*)((char*)Vt + c * 128 + ((o16 ^ (c & 7)) * 16));
      sh8 bv1 = *(sh8*)((char*)Vt + (32 + c) * 128 + ((o16 ^ ((32 + c) & 7)) * 16));
      o0 = __builtin_amdgcn_mfma_f32_32x32x16_bf16(ap, bv0, o0, 0, 0, 0);
      o1 = __builtin_amdgcn_mfma_f32_32x32x16_bf16(ap, bv1, o1, 0, 0, 0);
    }
  }

  #pragma unroll
  for (int i = 0; i < 16; i++) {
    int r = qb0 + w * 32 + (i & 3) + 8 * (i >> 2) + 4 * g;
    float inv = 1.0f / ll[i];
    short* yp = yb + (size_t)(b * cT + r) * cC + h * cHD;
    yp[c]      = f2bf(o0[i] * inv);
    yp[32 + c] = f2bf(o1[i] * inv);
  }
}

// ---------------- gate (bf16 h): logits, top-2, softmax, atomic routing ----------------
__global__ __launch_bounds__(256) void gate_k(const short* __restrict__ h2,
                                              const float* __restrict__ gw,
                                              float* __restrict__ selw,
                                              int* __restrict__ cnt, int* __restrict__ elist)
{
  int wv = threadIdx.x >> 6, lane = threadIdx.x & 63;
  int n = blockIdx.x * 4 + wv;
  float acc[8] = {0.f, 0.f, 0.f, 0.f, 0.f, 0.f, 0.f, 0.f};
  for (int c = lane; c < cC; c += 64) {
    float hv = bf2f(h2[(size_t)n * cC + c]);
    f4 g0 = *(const f4*)(gw + c * 8);
    f4 g1 = *(const f4*)(gw + c * 8 + 4);
    acc[0] = fmaf(hv, g0[0], acc[0]); acc[1] = fmaf(hv, g0[1], acc[1]);
    acc[2] = fmaf(hv, g0[2], acc[2]); acc[3] = fmaf(hv, g0[3], acc[3]);
    acc[4] = fmaf(hv, g1[0], acc[4]); acc[5] = fmaf(hv, g1[1], acc[5]);
    acc[6] = fmaf(hv, g1[2], acc[6]); acc[7] = fmaf(hv, g1[3], acc[7]);
  }
  #pragma unroll
  for (int e = 0; e < 8; e++)
    #pragma unroll
    for (int off = 32; off; off >>= 1) acc[e] += __shfl_xor(acc[e], off);
  if (lane == 0) {
    int i0 = 0; float m0 = acc[0];
    #pragma unroll
    for (int e = 1; e < 8; e++) if (acc[e] > m0) { m0 = acc[e]; i0 = e; }
    int i1 = -1; float m1 = -INFINITY;
    #pragma unroll
    for (int e = 0; e < 8; e++) if (e != i0 && acc[e] > m1) { m1 = acc[e]; i1 = e; }
    float e1 = expf(m1 - m0);
    float p0 = 1.f / (1.f + e1);
    float p1 = e1 / (1.f + e1);
    selw[n * 2] = p0;
    selw[n * 2 + 1] = p1;
    int pos0 = atomicAdd(&cnt[i0], 1); elist[(size_t)i0 * cN + pos0] = n * 2;
    int pos1 = atomicAdd(&cnt[i1], 1); elist[(size_t)i1 * cN + pos1] = n * 2 + 1;
  }
}

// ---------------- weighted combine ----------------
__global__ void combine_k(float* __restrict__ x, const float* __restrict__ eo,
                          const float* __restrict__ selw)
{
  int n = blockIdx.x, tid = threadIdx.x;
  float w0 = selw[n * 2], w1 = selw[n * 2 + 1];
  f4 a = *(const f4*)(eo + (size_t)(n * 2) * cC + tid * 4);
  f4 b = *(const f4*)(eo + (size_t)(n * 2 + 1) * cC + tid * 4);
  f4 xv = *(f4*)(x + (size_t)n * cC + tid * 4);
  xv += a * w0 + b * w1;
  *(f4*)(x + (size_t)n * cC + tid * 4) = xv;
}

// ---------------- logits (bf16 h, fp32 wte) ----------------
__global__ __launch_bounds__(256) void logits_k(const short* __restrict__ hf,
                                                const float* __restrict__ wte,
                                                float* __restrict__ out)
{
  int wv = threadIdx.x >> 6, lane = threadIdx.x & 63;
  int v = blockIdx.x * 4 + wv;
  const float* wrow = wte + (size_t)v * cC;
  const short* r0 = hf + (size_t)(cT - 1) * cC;
  const short* r1 = hf + (size_t)(2 * cT - 1) * cC;
  float a0 = 0.f, a1 = 0.f;
  for (int c = lane * 4; c < cC; c += 256) {
    f4 w4 = *(const f4*)(wrow + c);
    sh4 s0 = *(const sh4*)(r0 + c);
    sh4 s1 = *(const sh4*)(r1 + c);
    #pragma unroll
    for (int j = 0; j < 4; j++) {
      a0 = fmaf(w4[j], bf2f(s0[j]), a0);
      a1 = fmaf(w4[j], bf2f(s1[j]), a1);
    }
  }
  #pragma unroll
  for (int off = 32; off; off >>= 1) { a0 += __shfl_xor(a0, off); a1 += __shfl_xor(a1, off); }
  if (lane == 0) { out[v] = a0; out[cV + v] = a1; }
}

// =======================================================================
extern "C" void kernel_launch(void* const* d_in, const int* in_sizes, int n_in,
                              void* d_out, int out_size, void* d_ws, size_t ws_size,
                              hipStream_t stream)
{
  (void)in_sizes; (void)n_in; (void)out_size;
  const int*   idx  = (const int*)  d_in[0];
  const float* wte  = (const float*)d_in[1];
  const float* ln1w = (const float*)d_in[2];
  const float* p_wq = (const float*)d_in[3];
  const float* p_wk = (const float*)d_in[4];
  const float* p_wv = (const float*)d_in[5];
  const float* p_wo = (const float*)d_in[6];
  const float* ln2w = (const float*)d_in[7];
  const float* gw   = (const float*)d_in[8];
  const float* w1   = (const float*)d_in[9];
  const float* w2   = (const float*)d_in[10];
  const float* w3   = (const float*)d_in[11];
  const float* lnfw = (const float*)d_in[12];
  float* out = (float*)d_out;

  char* base = (char*)d_ws;
  size_t off = 0;
  auto alloc = [&](size_t bytes) { char* r = base + off; off = (off + bytes + 255) & ~(size_t)255; return r; };

  float* x    = (float*)alloc((size_t)cN * cC * 4);
  short* h    = (short*)alloc((size_t)cN * cC * 2);
  float* q    = (float*)alloc((size_t)cN * cC * 4);
  float* kbuf = (float*)alloc((size_t)cN * 512 * 4);
  float* vbuf = (float*)alloc((size_t)cN * 512 * 4);
  short* y    = (short*)alloc((size_t)cN * cC * 2);
  short* acts = (short*)alloc((size_t)cN * 2 * cHIDP * 2);
  float* eo   = (float*)alloc((size_t)cN * 2 * cC * 4);
  float* selw = (float*)alloc((size_t)cN * 2 * 4);
  int*   cnt  = (int*)  alloc(64);
  int*   elist= (int*)  alloc((size_t)cE * cN * 4);
  size_t smallNeed = off;
  short* wqT  = (short*)alloc((size_t)2 * 1024 * 1024 * 2);
  short* wkT  = (short*)alloc((size_t)2 * 512 * 1024 * 2);
  short* wvT  = (short*)alloc((size_t)2 * 512 * 1024 * 2);
  short* woT  = (short*)alloc((size_t)2 * 1024 * 1024 * 2);
  short* w1T  = (short*)alloc((size_t)cE * cHID * 1024 * 2);   // per-layer, reused
  short* w3T  = (short*)alloc((size_t)cE * cHID * 1024 * 2);
  short* w2T  = (short*)alloc((size_t)cE * 1024 * cHIDP * 2);
  bool big = (off <= ws_size);
  if (ws_size < smallNeed) return;

  embed_k<<<cN, 256, 0, stream>>>(idx, wte, x);
  if (big) {
    convT_k<<<dim3(32, 32, 2), 256, 0, stream>>>(p_wq, wqT, 1024, 1024, 1024);
    convT_k<<<dim3(32, 16, 2), 256, 0, stream>>>(p_wk, wkT, 1024, 512, 1024);
    convT_k<<<dim3(32, 16, 2), 256, 0, stream>>>(p_wv, wvT, 1024, 512, 1024);
    convT_k<<<dim3(32, 32, 2), 256, 0, stream>>>(p_wo, woT, 1024, 1024, 1024);
  }

  for (int l = 0; l < 2; l++) {
    // ---- attention ----
    rmsnorm_k<<<cN, 256, 0, stream>>>(x, ln1w + (size_t)l * cC, h);
    if (big) {
      mgemm<0,0,true><<<dim3(16, 8), 256, 0, stream>>>(h, wqT + (size_t)l * 1024 * 1024, q,
          cN, 1024, 1024, 1024, cC, 1024, 1024, nullptr, nullptr);
      mgemm<0,0,true><<<dim3(16, 4), 256, 0, stream>>>(h, wkT + (size_t)l * 512 * 1024, kbuf,
          cN, 512, 1024, 1024, cC, 1024, 512, nullptr, nullptr);
      mgemm<0,0,true><<<dim3(16, 4), 256, 0, stream>>>(h, wvT + (size_t)l * 512 * 1024, vbuf,
          cN, 512, 1024, 1024, cC, 1024, 512, nullptr, nullptr);
    } else {
      mgemm<0,0,false><<<dim3(16, 8), 256, 0, stream>>>(h, p_wq + (size_t)l * cC * 1024, q,
          cN, 1024, 1024, 1024, cC, 1024, 1024, nullptr, nullptr);
      mgemm<0,0,false><<<dim3(16, 4), 256, 0, stream>>>(h, p_wk + (size_t)l * cC * 512, kbuf,
          cN, 512, 1024, 1024, cC, 512, 512, nullptr, nullptr);
      mgemm<0,0,false><<<dim3(16, 4), 256, 0, stream>>>(h, p_wv + (size_t)l * cC * 512, vbuf,
          cN, 512, 1024, 1024, cC, 512, 512, nullptr, nullptr);
    }
    rope_k<<<(cN * cNH * 32) / 256, 256, 0, stream>>>(q, cNH);
    rope_k<<<(cN * cNKV * 32) / 256, 256, 0, stream>>>(kbuf, cNKV);
    attn_k<<<dim3(16, cNH, cB), 128, 0, stream>>>(q, kbuf, vbuf, y);
    if (big) {
      mgemm<1,0,true><<<dim3(16, 8), 256, 0, stream>>>(y, woT + (size_t)l * 1024 * 1024, x,
          cN, cC, 1024, 1024, 1024, 1024, cC, nullptr, nullptr);
    } else {
      mgemm<1,0,false><<<dim3(16, 8), 256, 0, stream>>>(y, p_wo + (size_t)l * 1024 * cC, x,
          cN, cC, 1024, 1024, 1024, cC, cC, nullptr, nullptr);
    }

    // ---- MoE ----
    rmsnorm_k<<<cN, 256, 0, stream>>>(x, ln2w + (size_t)l * cC, h);
    hipMemsetAsync(cnt, 0, cE * sizeof(int), stream);
    gate_k<<<cN / 4, 256, 0, stream>>>(h, gw + (size_t)l * cC * cE, selw, cnt, elist);
    if (big) {
      convT_k<<<dim3(32, 86, 8), 256, 0, stream>>>(w1 + (size_t)l * cE * cC * cHID, w1T,
          1024, cHID, 1024);
      convT_k<<<dim3(32, 86, 8), 256, 0, stream>>>(w3 + (size_t)l * cE * cC * cHID, w3T,
          1024, cHID, 1024);
      convT_k<<<dim3(86, 32, 8), 256, 0, stream>>>(w2 + (size_t)l * cE * cHID * cC, w2T,
          cHID, 1024, cHIDP);
      mgemm_ff<true><<<dim3(16, 22, 8), 256, 0, stream>>>(h, w1T, w3T, acts, elist, cnt);
      mgemm<0,2,true><<<dim3(16, 8, 8), 256, 0, stream>>>(acts, w2T, eo,
          0, 1024, cHIDP, cHID, cHIDP, cHIDP, 1024, elist, cnt);
    } else {
      mgemm_ff<false><<<dim3(16, 22, 8), 256, 0, stream>>>(h,
          w1 + (size_t)l * cE * cC * cHID, w3 + (size_t)l * cE * cC * cHID, acts, elist, cnt);
      mgemm<0,2,false><<<dim3(16, 8, 8), 256, 0, stream>>>(acts, w2 + (size_t)l * cE * cHID * cC, eo,
          0, 1024, cHIDP, cHID, cHIDP, 1024, 1024, elist, cnt);
    }
    combine_k<<<cN, 256, 0, stream>>>(x, eo, selw);
  }

  rmsnorm_k<<<cN, 256, 0, stream>>>(x, lnfw, h);
  logits_k<<<cV / 4, 256, 0, stream>>>(h, wte, out);
}

// Round 6
// 1198.110 us; speedup vs baseline: 1.8003x; 1.3050x over previous
//
#include <hip/hip_runtime.h>
#include <hip/hip_bf16.h>
#include <math.h>

using f4 = __attribute__((ext_vector_type(4))) float;
using f16x = __attribute__((ext_vector_type(16))) float;
using sh4 = __attribute__((ext_vector_type(4))) short;
using sh8 = __attribute__((ext_vector_type(8))) short;

constexpr int cV = 32000, cC = 1024;
constexpr int cNH = 16, cNKV = 8, cHD = 64;
constexpr int cE = 8, cHID = 2728;
constexpr int cHIDP = 2752;              // K-pad for w2 (multiple of 64)
constexpr int cHIDR = 2816;              // row-pad for w1T/w3T slabs (multiple of 128)
constexpr int cB = 2, cT = 1024, cN = cB * cT;

__device__ inline float dot4(f4 a, f4 b) { return a[0]*b[0] + a[1]*b[1] + a[2]*b[2] + a[3]*b[3]; }

__device__ inline short f2bf(float f) {
  unsigned u = __builtin_bit_cast(unsigned, f);
  u += 0x7fff + ((u >> 16) & 1);          // RNE
  return (short)(u >> 16);
}
__device__ inline float bf2f(short s) {
  return __builtin_bit_cast(float, ((unsigned)(unsigned short)s) << 16);
}

// async global->LDS, 16B per lane; LDS dest is wave-uniform base + lane*16 (m97).
__device__ __forceinline__ void gl16(const void* g, void* l) {
  __builtin_amdgcn_global_load_lds((const __attribute__((address_space(1))) void*)g,
                                   (__attribute__((address_space(3))) void*)l, 16, 0, 0);
}

// ---------------- embedding gather ----------------
__global__ void embed_k(const int* __restrict__ idx, const float* __restrict__ wte,
                        float* __restrict__ x)
{
  int n = blockIdx.x, tid = threadIdx.x;
  size_t row = (size_t)idx[n] * cC;
  *(f4*)(x + (size_t)n * cC + tid * 4) = *(const f4*)(wte + row + tid * 4);
}

// ---------------- rmsnorm (fp32 in, bf16 out) ----------------
__global__ __launch_bounds__(256) void rmsnorm_k(const float* __restrict__ in,
                                                 const float* __restrict__ w,
                                                 short* __restrict__ out)
{
  int n = blockIdx.x, tid = threadIdx.x;
  f4 v = *(const f4*)(in + (size_t)n * cC + tid * 4);
  float s = dot4(v, v);
  #pragma unroll
  for (int off = 32; off; off >>= 1) s += __shfl_xor(s, off);
  __shared__ float red[4];
  if ((tid & 63) == 0) red[tid >> 6] = s;
  __syncthreads();
  float tot = red[0] + red[1] + red[2] + red[3];
  float inv = rsqrtf(tot * (1.0f / cC) + 1e-5f);
  f4 wv = *(const f4*)(w + tid * 4);
  f4 o = v * inv * wv;
  sh4 ov = { f2bf(o[0]), f2bf(o[1]), f2bf(o[2]), f2bf(o[3]) };
  *(sh4*)(out + (size_t)n * cC + tid * 4) = ov;
}

// ------- transpose + fp32->bf16: src[K][N] -> dst[N][Kp], zero-fill k in [K,Kp) -------
__global__ __launch_bounds__(256) void convT_k(const float* __restrict__ src,
                                               short* __restrict__ dst,
                                               int K, int N, int Kp,
                                               size_t zsS, size_t zsD)
{
  src += (size_t)blockIdx.z * zsS;
  dst += (size_t)blockIdx.z * zsD;
  int k0 = blockIdx.x * 32, n0 = blockIdx.y * 32;
  __shared__ float T[32][33];
  int r = threadIdx.x >> 3, cq = (threadIdx.x & 7) * 4;
  f4 v = {0.f, 0.f, 0.f, 0.f};
  if (k0 + r < K && n0 + cq < N)
    v = *(const f4*)(src + (size_t)(k0 + r) * N + n0 + cq);
  T[r][cq + 0] = v[0]; T[r][cq + 1] = v[1]; T[r][cq + 2] = v[2]; T[r][cq + 3] = v[3];
  __syncthreads();
  int n = n0 + r;
  if (n < N) {
    sh4 ov = { f2bf(T[cq + 0][r]), f2bf(T[cq + 1][r]), f2bf(T[cq + 2][r]), f2bf(T[cq + 3][r]) };
    *(sh4*)(dst + (size_t)n * Kp + k0 + cq) = ov;
  }
}

// ====== m97-style bf16 GEMM: 128x128 tile, BK=64, global_load_lds, swizzled ======
// A bf16 [row][lda], B bf16 [n][ldb] (pre-transposed). LDS linear, source pre-swizzle
// slot ^= row&7 within 128B rows -> conflict-free ds_read_b128 (rule 21 / m173).
// EPI: 0 f32 store, 1 f32 +=, 2 bf16 qkv split-store. GATH: 0 dense, 2 A/C row = list[m].
template<int EPI, int GATH>
__global__ __launch_bounds__(256, 3) void ggemm(
    const short* __restrict__ Ab, const short* __restrict__ Bt,
    float* __restrict__ Cf, short* __restrict__ Cq, short* __restrict__ Ck,
    short* __restrict__ Cv,
    int M, int Nc, int K, int lda, int ldb, int ldc, size_t bz,
    const int* __restrict__ gidx, const int* __restrict__ gcnt)
{
  int Me = M;
  const int* idxp = nullptr;
  const short* Bte = Bt;
  if (GATH) {
    int e = blockIdx.z;
    Me = gcnt[e];
    idxp = gidx + (size_t)e * cN;
    Bte += (size_t)e * bz;
  }
  int m0 = blockIdx.x * 128;
  if (m0 >= Me) return;
  int n0 = blockIdx.y * 128;

  __shared__ short As[128 * 64];
  __shared__ short Bs[128 * 64];

  int tid = threadIdx.x, l = tid & 63, w = tid >> 6;
  int wr = w >> 1, wc = w & 1;
  int lq = l >> 3, ls = l & 7;

  const short* aptr[4];
  const short* bptr[4];
  #pragma unroll
  for (int i = 0; i < 4; i++) {
    int cA = w * 4 + i;
    int rA = cA * 8 + lq;
    int arow;
    if (GATH) { int mr = m0 + rA; if (mr >= Me) mr = Me - 1; arow = idxp[mr]; }
    else arow = m0 + rA;
    int swz = (ls ^ (rA & 7)) * 8;
    aptr[i] = Ab + (size_t)arow * lda + swz;
    bptr[i] = Bte + (size_t)(n0 + rA) * ldb + swz;
  }

  f4 acc[4][4] = {};
  int fr = l & 15, fq = l >> 4;

  for (int k0 = 0; k0 < K; k0 += 64) {
    #pragma unroll
    for (int i = 0; i < 4; i++) {
      gl16(aptr[i] + k0, As + (w * 4 + i) * 512);
      gl16(bptr[i] + k0, Bs + (w * 4 + i) * 512);
    }
    __syncthreads();                    // drains vmcnt -> tile ready
    #pragma unroll
    for (int kk = 0; kk < 2; kk++) {
      sh8 af[4], bf[4];
      #pragma unroll
      for (int m = 0; m < 4; m++) {
        int r = wr * 64 + m * 16 + fr;
        af[m] = *(const sh8*)(As + r * 64 + (((kk * 4 + fq) ^ (r & 7)) * 8));
      }
      #pragma unroll
      for (int n = 0; n < 4; n++) {
        int r = wc * 64 + n * 16 + fr;
        bf[n] = *(const sh8*)(Bs + r * 64 + (((kk * 4 + fq) ^ (r & 7)) * 8));
      }
      #pragma unroll
      for (int m = 0; m < 4; m++)
        #pragma unroll
        for (int n = 0; n < 4; n++)
          acc[m][n] = __builtin_amdgcn_mfma_f32_16x16x32_bf16(af[m], bf[n], acc[m][n], 0, 0, 0);
    }
    __syncthreads();                    // reads done before next overwrite
  }

  int rq = fq * 4;
  #pragma unroll
  for (int m = 0; m < 4; m++) {
    #pragma unroll
    for (int i = 0; i < 4; i++) {
      int mrow = m0 + wr * 64 + m * 16 + rq + i;
      if (GATH && mrow >= Me) continue;
      size_t crow = (size_t)(GATH ? idxp[mrow] : mrow);
      #pragma unroll
      for (int n = 0; n < 4; n++) {
        int ncol = n0 + wc * 64 + n * 16 + fr;
        float vv = acc[m][n][i];
        if (EPI == 2) {
          short s = f2bf(vv);
          if (ncol < 1024)      Cq[crow * 1024 + ncol] = s;
          else if (ncol < 1536) Ck[crow * 512 + (ncol - 1024)] = s;
          else                  Cv[crow * 512 + (ncol - 1536)] = s;
        } else if (EPI == 0) Cf[crow * ldc + ncol] = vv;
        else                 Cf[crow * ldc + ncol] += vv;
      }
    }
  }
}

// ====== fused w1+w3 gather GEMM (same structure): acts = silu(h@w1)*(h@w3), bf16 ======
__global__ __launch_bounds__(256, 2) void gg_ff(
    const short* __restrict__ Ab, const short* __restrict__ B1t, const short* __restrict__ B3t,
    short* __restrict__ actsOut,
    const int* __restrict__ gidx, const int* __restrict__ gcnt)
{
  constexpr int K = cC, ldb = cC, lda = cC;
  int e = blockIdx.z;
  int Me = gcnt[e];
  const int* idxp = gidx + (size_t)e * cN;
  int m0 = blockIdx.x * 128;
  if (m0 >= Me) return;
  int n0 = blockIdx.y * 128;
  const short* B1e = B1t + (size_t)e * cHIDR * ldb;
  const short* B3e = B3t + (size_t)e * cHIDR * ldb;

  __shared__ short As[128 * 64];
  __shared__ short Bs1[128 * 64];
  __shared__ short Bs3[128 * 64];

  int tid = threadIdx.x, l = tid & 63, w = tid >> 6;
  int wr = w >> 1, wc = w & 1;
  int lq = l >> 3, ls = l & 7;

  const short* aptr[4];
  const short* b1ptr[4];
  const short* b3ptr[4];
  #pragma unroll
  for (int i = 0; i < 4; i++) {
    int cA = w * 4 + i;
    int rA = cA * 8 + lq;
    int mr = m0 + rA; if (mr >= Me) mr = Me - 1;
    int token = idxp[mr] >> 1;
    int swz = (ls ^ (rA & 7)) * 8;
    aptr[i]  = Ab + (size_t)token * lda + swz;
    b1ptr[i] = B1e + (size_t)(n0 + rA) * ldb + swz;   // rows padded to cHIDR
    b3ptr[i] = B3e + (size_t)(n0 + rA) * ldb + swz;
  }

  f4 acc1[4][4] = {}, acc3[4][4] = {};
  int fr = l & 15, fq = l >> 4;

  for (int k0 = 0; k0 < K; k0 += 64) {
    #pragma unroll
    for (int i = 0; i < 4; i++) {
      gl16(aptr[i] + k0,  As  + (w * 4 + i) * 512);
      gl16(b1ptr[i] + k0, Bs1 + (w * 4 + i) * 512);
      gl16(b3ptr[i] + k0, Bs3 + (w * 4 + i) * 512);
    }
    __syncthreads();
    #pragma unroll
    for (int kk = 0; kk < 2; kk++) {
      sh8 af[4], bf1[4], bf3[4];
      #pragma unroll
      for (int m = 0; m < 4; m++) {
        int r = wr * 64 + m * 16 + fr;
        af[m] = *(const sh8*)(As + r * 64 + (((kk * 4 + fq) ^ (r & 7)) * 8));
      }
      #pragma unroll
      for (int n = 0; n < 4; n++) {
        int r = wc * 64 + n * 16 + fr;
        int so = ((kk * 4 + fq) ^ (r & 7)) * 8;
        bf1[n] = *(const sh8*)(Bs1 + r * 64 + so);
        bf3[n] = *(const sh8*)(Bs3 + r * 64 + so);
      }
      #pragma unroll
      for (int m = 0; m < 4; m++)
        #pragma unroll
        for (int n = 0; n < 4; n++) {
          acc1[m][n] = __builtin_amdgcn_mfma_f32_16x16x32_bf16(af[m], bf1[n], acc1[m][n], 0, 0, 0);
          acc3[m][n] = __builtin_amdgcn_mfma_f32_16x16x32_bf16(af[m], bf3[n], acc3[m][n], 0, 0, 0);
        }
    }
    __syncthreads();
  }

  int rq = fq * 4;
  #pragma unroll
  for (int m = 0; m < 4; m++) {
    #pragma unroll
    for (int i = 0; i < 4; i++) {
      int mrow = m0 + wr * 64 + m * 16 + rq + i;
      if (mrow >= Me) continue;
      size_t crow = (size_t)idxp[mrow] * cHIDP;
      #pragma unroll
      for (int n = 0; n < 4; n++) {
        int ncol = n0 + wc * 64 + n * 16 + fr;
        if (ncol < cHID) {
          float a1 = acc1[m][n][i], a3 = acc3[m][n][i];
          actsOut[crow + ncol] = f2bf(a1 / (1.f + __expf(-a1)) * a3);
        } else if (ncol < cHIDP) {
          actsOut[crow + ncol] = 0;     // zero K-pad for w2
        }
      }
    }
  }
}

// ---------------- RoPE in place on bf16 [N, nh*64] ----------------
__global__ void rope_k(short* __restrict__ buf, int nh)
{
  int gid = blockIdx.x * 256 + threadIdx.x;
  int i = gid & 31;
  int rest = gid >> 5;
  int h = rest % nh;
  int n = rest / nh;
  int t = n & (cT - 1);
  float fr = __expf(-(float)i * (9.210340371976184f / 32.f));
  float ang = (float)t * fr;
  float sn, cs;
  sincosf(ang, &sn, &cs);
  short* p = buf + (size_t)n * (nh * cHD) + h * cHD + 2 * i;
  float r0 = bf2f(p[0]), r1 = bf2f(p[1]);
  p[0] = f2bf(r0 * cs - r1 * sn);
  p[1] = f2bf(r0 * sn + r1 * cs);
}

// ======== MFMA flash attention (bf16 q/k/v): 64 q-rows, 2 waves x 32 ========
__global__ __launch_bounds__(128) void attn_k(const short* __restrict__ qb,
                                              const short* __restrict__ kb,
                                              const short* __restrict__ vb,
                                              short* __restrict__ yb)
{
  int h = blockIdx.y, b = blockIdx.z;
  int qt = (b == 1) ? (15 - blockIdx.x) : blockIdx.x;   // causal load balance
  int qb0 = qt * 64;
  int kvh = h >> 1;                        // n_rep = 2
  int tid = threadIdx.x, w = tid >> 6, l = tid & 63;
  int c = l & 31, g = l >> 5;

  __shared__ short Kl[64 * 64];            // [key][d], swizzled 16B slots
  __shared__ short Vt[64 * 64];            // [d][key], swizzled
  __shared__ short Pl[2][32 * 64];         // per-wave P, swizzled

  sh8 aq[4];
  {
    const short* qp = qb + (size_t)(b * cT + qb0 + w * 32 + c) * cC + h * cHD + g * 8;
    #pragma unroll
    for (int k = 0; k < 4; k++) aq[k] = *(const sh8*)(qp + k * 16);
  }

  float m[16], ll[16];
  f16x o0 = {}, o1 = {};
  #pragma unroll
  for (int i = 0; i < 16; i++) { m[i] = -1e30f; ll[i] = 0.f; }

  for (int kt = 0; kt <= qb0; kt += 64) {
    __syncthreads();
    // ---- K via global_load_lds, source pre-swizzled ----
    #pragma unroll
    for (int i = 0; i < 4; i++) {
      int cK = w * 4 + i;
      int rK = cK * 8 + (l >> 3);
      const short* src = kb + (size_t)(b * cT + kt + rK) * 512 + kvh * 64
                       + (((l & 7) ^ (rK & 7)) * 8);
      gl16(src, Kl + cK * 512);
    }
    // ---- V transposed: Vt[d][key], packed pairs ----
    {
      int p = tid & 31, dh = tid >> 5;
      const short* v0 = vb + (size_t)(b * cT + kt + 2 * p) * 512 + kvh * 64 + dh * 16;
      const short* v1 = v0 + 512;
      sh8 a0 = *(const sh8*)v0, a1 = *(const sh8*)(v0 + 8);
      sh8 c0 = *(const sh8*)v1, c1 = *(const sh8*)(v1 + 8);
      #pragma unroll
      for (int j = 0; j < 16; j++) {
        int d = dh * 16 + j;
        unsigned lo = (unsigned)(unsigned short)(j < 8 ? a0[j] : a1[j - 8]);
        unsigned hi = (unsigned)(unsigned short)(j < 8 ? c0[j] : c1[j - 8]);
        *(unsigned*)((char*)Vt + d * 128 + ((p * 4) ^ ((d & 7) << 4))) = lo | (hi << 16);
      }
    }
    __syncthreads();

    f16x s0 = {}, s1 = {};
    #pragma unroll
    for (int k = 0; k < 4; k++) {
      int o16 = k * 2 + g;
      sh8 b0 = *(sh8*)((char*)Kl + c * 128 + ((o16 ^ (c & 7)) * 16));
      sh8 b1 = *(sh8*)((char*)Kl + (32 + c) * 128 + ((o16 ^ ((32 + c) & 7)) * 16));
      s0 = __builtin_amdgcn_mfma_f32_32x32x16_bf16(aq[k], b0, s0, 0, 0, 0);
      s1 = __builtin_amdgcn_mfma_f32_32x32x16_bf16(aq[k], b1, s1, 0, 0, 0);
    }
    #pragma unroll
    for (int i = 0; i < 16; i++) { s0[i] *= 0.125f; s1[i] *= 0.125f; }   // 1/sqrt(64)

    if (kt + 63 > qb0 + w * 32) {
      #pragma unroll
      for (int i = 0; i < 16; i++) {
        int r = qb0 + w * 32 + (i & 3) + 8 * (i >> 2) + 4 * g;
        if (kt + c > r)      s0[i] = -1e30f;
        if (kt + 32 + c > r) s1[i] = -1e30f;
      }
    }

    #pragma unroll
    for (int i = 0; i < 16; i++) {
      float mt = fmaxf(s0[i], s1[i]);
      #pragma unroll
      for (int off = 1; off < 32; off <<= 1) mt = fmaxf(mt, __shfl_xor(mt, off));
      float mn = fmaxf(m[i], mt);
      float rs = __expf(m[i] - mn);
      m[i] = mn;
      float p0 = __expf(s0[i] - mn);
      float p1 = __expf(s1[i] - mn);
      s0[i] = p0; s1[i] = p1;
      float ps = p0 + p1;
      #pragma unroll
      for (int off = 1; off < 32; off <<= 1) ps += __shfl_xor(ps, off);
      ll[i] = ll[i] * rs + ps;
      o0[i] *= rs; o1[i] *= rs;
    }

    #pragma unroll
    for (int i = 0; i < 16; i++) {
      int r = (i & 3) + 8 * (i >> 2) + 4 * g;
      *(short*)((char*)Pl[w] + r * 128 + ((c * 2) ^ ((r & 7) << 4)))        = f2bf(s0[i]);
      *(short*)((char*)Pl[w] + r * 128 + (((32 + c) * 2) ^ ((r & 7) << 4))) = f2bf(s1[i]);
    }

    #pragma unroll
    for (int k = 0; k < 4; k++) {
      int o16 = k * 2 + g;
      sh8 ap  = *(sh8*)((char*)Pl[w] + c * 128 + ((o16 ^ (c & 7)) * 16));
      sh8 bv0 = *(sh8*)((char*)Vt + c * 128 + ((o16 ^ (c & 7)) * 16));
      sh8 bv1 = *(sh8*)((char*)Vt + (32 + c) * 128 + ((o16 ^ ((32 + c) & 7)) * 16));
      o0 = __builtin_amdgcn_mfma_f32_32x32x16_bf16(ap, bv0, o0, 0, 0, 0);
      o1 = __builtin_amdgcn_mfma_f32_32x32x16_bf16(ap, bv1, o1, 0, 0, 0);
    }
  }

  #pragma unroll
  for (int i = 0; i < 16; i++) {
    int r = qb0 + w * 32 + (i & 3) + 8 * (i >> 2) + 4 * g;
    float inv = 1.0f / ll[i];
    short* yp = yb + (size_t)(b * cT + r) * cC + h * cHD;
    yp[c]      = f2bf(o0[i] * inv);
    yp[32 + c] = f2bf(o1[i] * inv);
  }
}

// ---------------- gate (bf16 h): top-2 + softmax + atomic routing ----------------
__global__ __launch_bounds__(256) void gate_k(const short* __restrict__ h2,
                                              const float* __restrict__ gw,
                                              float* __restrict__ selw,
                                              int* __restrict__ cnt, int* __restrict__ elist)
{
  int wv = threadIdx.x >> 6, lane = threadIdx.x & 63;
  int n = blockIdx.x * 4 + wv;
  float acc[8] = {0.f, 0.f, 0.f, 0.f, 0.f, 0.f, 0.f, 0.f};
  for (int c = lane; c < cC; c += 64) {
    float hv = bf2f(h2[(size_t)n * cC + c]);
    f4 g0 = *(const f4*)(gw + c * 8);
    f4 g1 = *(const f4*)(gw + c * 8 + 4);
    acc[0] = fmaf(hv, g0[0], acc[0]); acc[1] = fmaf(hv, g0[1], acc[1]);
    acc[2] = fmaf(hv, g0[2], acc[2]); acc[3] = fmaf(hv, g0[3], acc[3]);
    acc[4] = fmaf(hv, g1[0], acc[4]); acc[5] = fmaf(hv, g1[1], acc[5]);
    acc[6] = fmaf(hv, g1[2], acc[6]); acc[7] = fmaf(hv, g1[3], acc[7]);
  }
  #pragma unroll
  for (int e = 0; e < 8; e++)
    #pragma unroll
    for (int off = 32; off; off >>= 1) acc[e] += __shfl_xor(acc[e], off);
  if (lane == 0) {
    int i0 = 0; float m0 = acc[0];
    #pragma unroll
    for (int e = 1; e < 8; e++) if (acc[e] > m0) { m0 = acc[e]; i0 = e; }
    int i1 = -1; float m1 = -INFINITY;
    #pragma unroll
    for (int e = 0; e < 8; e++) if (e != i0 && acc[e] > m1) { m1 = acc[e]; i1 = e; }
    float e1 = expf(m1 - m0);
    selw[n * 2]     = 1.f / (1.f + e1);
    selw[n * 2 + 1] = e1 / (1.f + e1);
    int pos0 = atomicAdd(&cnt[i0], 1); elist[(size_t)i0 * cN + pos0] = n * 2;
    int pos1 = atomicAdd(&cnt[i1], 1); elist[(size_t)i1 * cN + pos1] = n * 2 + 1;
  }
}

// ---------------- weighted combine ----------------
__global__ void combine_k(float* __restrict__ x, const float* __restrict__ eo,
                          const float* __restrict__ selw)
{
  int n = blockIdx.x, tid = threadIdx.x;
  float w0 = selw[n * 2], w1 = selw[n * 2 + 1];
  f4 a = *(const f4*)(eo + (size_t)(n * 2) * cC + tid * 4);
  f4 b = *(const f4*)(eo + (size_t)(n * 2 + 1) * cC + tid * 4);
  f4 xv = *(f4*)(x + (size_t)n * cC + tid * 4);
  xv += a * w0 + b * w1;
  *(f4*)(x + (size_t)n * cC + tid * 4) = xv;
}

// ---------------- logits (bf16 h, fp32 wte) ----------------
__global__ __launch_bounds__(256) void logits_k(const short* __restrict__ hf,
                                                const float* __restrict__ wte,
                                                float* __restrict__ out)
{
  int wv = threadIdx.x >> 6, lane = threadIdx.x & 63;
  int v = blockIdx.x * 4 + wv;
  const float* wrow = wte + (size_t)v * cC;
  const short* r0 = hf + (size_t)(cT - 1) * cC;
  const short* r1 = hf + (size_t)(2 * cT - 1) * cC;
  float a0 = 0.f, a1 = 0.f;
  for (int c = lane * 4; c < cC; c += 256) {
    f4 w4 = *(const f4*)(wrow + c);
    sh4 s0 = *(const sh4*)(r0 + c);
    sh4 s1 = *(const sh4*)(r1 + c);
    #pragma unroll
    for (int j = 0; j < 4; j++) {
      a0 = fmaf(w4[j], bf2f(s0[j]), a0);
      a1 = fmaf(w4[j], bf2f(s1[j]), a1);
    }
  }
  #pragma unroll
  for (int off = 32; off; off >>= 1) { a0 += __shfl_xor(a0, off); a1 += __shfl_xor(a1, off); }
  if (lane == 0) { out[v] = a0; out[cV + v] = a1; }
}

// =======================================================================
extern "C" void kernel_launch(void* const* d_in, const int* in_sizes, int n_in,
                              void* d_out, int out_size, void* d_ws, size_t ws_size,
                              hipStream_t stream)
{
  (void)in_sizes; (void)n_in; (void)out_size;
  const int*   idx  = (const int*)  d_in[0];
  const float* wte  = (const float*)d_in[1];
  const float* ln1w = (const float*)d_in[2];
  const float* p_wq = (const float*)d_in[3];
  const float* p_wk = (const float*)d_in[4];
  const float* p_wv = (const float*)d_in[5];
  const float* p_wo = (const float*)d_in[6];
  const float* ln2w = (const float*)d_in[7];
  const float* gw   = (const float*)d_in[8];
  const float* w1   = (const float*)d_in[9];
  const float* w2   = (const float*)d_in[10];
  const float* w3   = (const float*)d_in[11];
  const float* lnfw = (const float*)d_in[12];
  float* out = (float*)d_out;

  char* base = (char*)d_ws;
  size_t off = 0;
  auto alloc = [&](size_t bytes) { char* r = base + off; off = (off + bytes + 255) & ~(size_t)255; return r; };

  float* x     = (float*)alloc((size_t)cN * cC * 4);
  short* h     = (short*)alloc((size_t)cN * cC * 2);
  short* q     = (short*)alloc((size_t)cN * cC * 2);
  short* kbuf  = (short*)alloc((size_t)cN * 512 * 2);
  short* vbuf  = (short*)alloc((size_t)cN * 512 * 2);
  short* y     = (short*)alloc((size_t)cN * cC * 2);
  short* acts  = (short*)alloc((size_t)cN * 2 * cHIDP * 2);
  float* eo    = (float*)alloc((size_t)cN * 2 * cC * 4);
  float* selw  = (float*)alloc((size_t)cN * 2 * 4);
  int*   cnt   = (int*)  alloc(64);
  int*   elist = (int*)  alloc((size_t)cE * cN * 4);
  short* wqkvT = (short*)alloc((size_t)2 * 2048 * 1024 * 2);   // q|k|v rows, per layer
  short* woT   = (short*)alloc((size_t)2 * 1024 * 1024 * 2);
  short* w1T   = (short*)alloc((size_t)cE * cHIDR * 1024 * 2); // per-layer, reused
  short* w3T   = (short*)alloc((size_t)cE * cHIDR * 1024 * 2);
  short* w2T   = (short*)alloc((size_t)cE * 1024 * cHIDP * 2);
  if (ws_size < off) return;   // ~215 MB (fit demonstrated at 220 MB in r5)

  embed_k<<<cN, 256, 0, stream>>>(idx, wte, x);
  // QKV/WO weights: transpose+bf16 once (both layers)
  convT_k<<<dim3(32, 32, 2), 256, 0, stream>>>(p_wq, wqkvT, 1024, 1024, 1024,
      (size_t)1024 * 1024, (size_t)2048 * 1024);
  convT_k<<<dim3(32, 16, 2), 256, 0, stream>>>(p_wk, wqkvT + (size_t)1024 * 1024, 1024, 512, 1024,
      (size_t)1024 * 512, (size_t)2048 * 1024);
  convT_k<<<dim3(32, 16, 2), 256, 0, stream>>>(p_wv, wqkvT + (size_t)1536 * 1024, 1024, 512, 1024,
      (size_t)1024 * 512, (size_t)2048 * 1024);
  convT_k<<<dim3(32, 32, 2), 256, 0, stream>>>(p_wo, woT, 1024, 1024, 1024,
      (size_t)1024 * 1024, (size_t)1024 * 1024);

  for (int l = 0; l < 2; l++) {
    // ---- attention ----
    rmsnorm_k<<<cN, 256, 0, stream>>>(x, ln1w + (size_t)l * cC, h);
    ggemm<2,0><<<dim3(16, 16), 256, 0, stream>>>(h, wqkvT + (size_t)l * 2048 * 1024,
        nullptr, q, kbuf, vbuf, cN, 2048, 1024, 1024, 1024, 0, 0, nullptr, nullptr);
    rope_k<<<(cN * cNH * 32) / 256, 256, 0, stream>>>(q, cNH);
    rope_k<<<(cN * cNKV * 32) / 256, 256, 0, stream>>>(kbuf, cNKV);
    attn_k<<<dim3(16, cNH, cB), 128, 0, stream>>>(q, kbuf, vbuf, y);
    ggemm<1,0><<<dim3(16, 8), 256, 0, stream>>>(y, woT + (size_t)l * 1024 * 1024,
        x, nullptr, nullptr, nullptr, cN, 1024, 1024, 1024, 1024, 1024, 0, nullptr, nullptr);

    // ---- MoE ----
    rmsnorm_k<<<cN, 256, 0, stream>>>(x, ln2w + (size_t)l * cC, h);
    hipMemsetAsync(cnt, 0, cE * sizeof(int), stream);
    gate_k<<<cN / 4, 256, 0, stream>>>(h, gw + (size_t)l * cC * cE, selw, cnt, elist);
    convT_k<<<dim3(32, 86, 8), 256, 0, stream>>>(w1 + (size_t)l * cE * cC * cHID, w1T,
        1024, cHID, 1024, (size_t)1024 * cHID, (size_t)cHIDR * 1024);
    convT_k<<<dim3(32, 86, 8), 256, 0, stream>>>(w3 + (size_t)l * cE * cC * cHID, w3T,
        1024, cHID, 1024, (size_t)1024 * cHID, (size_t)cHIDR * 1024);
    convT_k<<<dim3(86, 32, 8), 256, 0, stream>>>(w2 + (size_t)l * cE * cHID * cC, w2T,
        cHID, 1024, cHIDP, (size_t)cHID * 1024, (size_t)1024 * cHIDP);
    gg_ff<<<dim3(16, 22, 8), 256, 0, stream>>>(h, w1T, w3T, acts, elist, cnt);
    ggemm<0,2><<<dim3(16, 8, 8), 256, 0, stream>>>(acts, w2T, eo, nullptr, nullptr, nullptr,
        0, 1024, cHIDP, cHIDP, cHIDP, 1024, (size_t)1024 * cHIDP, elist, cnt);
    combine_k<<<cN, 256, 0, stream>>>(x, eo, selw);
  }

  rmsnorm_k<<<cN, 256, 0, stream>>>(x, lnfw, h);
  logits_k<<<cV / 4, 256, 0, stream>>>(h, wte, out);
}